// Round 3
// baseline (1565.898 us; speedup 1.0000x reference)
//
#include <hip/hip_runtime.h>
#include <hip/hip_cooperative_groups.h>
#include <math.h>

namespace cg = cooperative_groups;

#define NNODES 100000
#define B 4096
#define M 256
#define UB 16
#define ROWP 264
#define NROUNDS 12
#define NOTDONE 0x7fffffff
#define ALPHA 0.1f
#define NBLK 256
#define NTHR 1024

typedef __attribute__((ext_vector_type(8))) short short8;
typedef __attribute__((ext_vector_type(4))) short short4v;
typedef __attribute__((ext_vector_type(4))) float f32x4;

__device__ __forceinline__ short bf16rne(float x) {
    union { float f; unsigned u; } v; v.f = x;
    unsigned r = v.u + 0x7fffu + ((v.u >> 16) & 1u);
    return (short)(r >> 16);
}
__device__ __forceinline__ float bf2f(short h) {
    union { unsigned u; float f; } v; v.u = ((unsigned)(unsigned short)h) << 16;
    return v.f;
}
__device__ __forceinline__ void split2(float x, short &hi, short &lo) {
    hi = bf16rne(x);
    lo = bf16rne(x - bf2f(hi));
}

struct GemmSh {
    short psH[UB * ROWP]; short psL[UB * ROWP];
    short pdH[UB * ROWP]; short pdL[UB * ROWP];
    short xH[UB * ROWP];  short xL[UB * ROWP];
};
struct DepSh { int sL[B]; int dL[B]; };

// ---------------------------------------------------------------------------
// Single cooperative kernel: phase 0 = weight bf16 casts + dep scan + init;
// then NROUNDS wavefront rounds separated by grid.sync().
// Block b owns steps [16b, 16b+16); wave w owns output cols [16w, 16w+16).
// MFMA 16x16x32 bf16 with hi/lo-split activations (fp32-accurate to ~2^-17).
// ---------------------------------------------------------------------------
__global__ __launch_bounds__(NTHR, 4) void tgn_main(
    const int* __restrict__ src, const int* __restrict__ dst,
    const float* __restrict__ ef, const int* __restrict__ tsi,
    const float* __restrict__ lu0,
    const float* __restrict__ W1g, const float* __restrict__ W2g,
    const float* __restrict__ wihG, const float* __restrict__ whhG,
    const float* __restrict__ b1, const float* __restrict__ b2,
    const float* __restrict__ bih, const float* __restrict__ bhh,
    short* __restrict__ W1h, short* __restrict__ W2h,
    short* __restrict__ wihH, short* __restrict__ whhH,
    int* done_round, float* mem)
{
    __shared__ __align__(16) union { GemmSh g; DepSh d; } sh;
    __shared__ float efs[UB][3];
    __shared__ float decS[UB], decD[UB];
    __shared__ int sA[UB], dA[UB], actA[UB];
    __shared__ int depS[UB], depD[UB];

    cg::grid_group grid = cg::this_grid();
    int tid = threadIdx.x;
    int bx = blockIdx.x;
    int gtid = bx * NTHR + tid;
    const int gthreads = NBLK * NTHR;

    // ---- phase 0: weight casts (grid-stride), dep staging + scan, init ----
    for (int t = gtid; t < 256 * 512; t += gthreads) {
        int n = t >> 9, k = t & 511;
        W1h[t] = bf16rne(W1g[n * 515 + k]);
    }
    for (int t = gtid; t < 256 * 256; t += gthreads) W2h[t] = bf16rne(W2g[t]);
    for (int t = gtid; t < 768 * 256; t += gthreads) {
        wihH[t] = bf16rne(wihG[t]); whhH[t] = bf16rne(whhG[t]);
    }
    for (int j = tid; j < B; j += NTHR) { sh.d.sL[j] = src[j]; sh.d.dL[j] = dst[j]; }
    if (tid < UB) done_round[bx * UB + tid] = NOTDONE;
    __syncthreads();

    {   // one wave per step: lockstep backward scan, ballot for latest match
        int wv = tid >> 6, lane = tid & 63;
        int i = bx * UB + wv;
        int vs = sh.d.sL[i], vd = sh.d.dL[i];
        int bs = -1, bd = -1;
        for (int base = i - 1; base >= 0; base -= 64) {
            int j = base - lane;
            bool okj = (j >= 0);
            int sj = okj ? sh.d.sL[j] : -1;
            int dj = okj ? sh.d.dL[j] : -1;
            if (bs < 0) {
                unsigned long long mk = __ballot(okj && (sj == vs || dj == vs));
                if (mk) bs = base - (int)__builtin_ctzll(mk);
            }
            if (bd < 0) {
                unsigned long long mk = __ballot(okj && (sj == vd || dj == vd));
                if (mk) bd = base - (int)__builtin_ctzll(mk);
            }
            if (bs >= 0 && bd >= 0) break;
        }
        if (lane == 0) { depS[wv] = bs; depD[wv] = bd; }
    }
    __threadfence();
    grid.sync();

    int wav = tid >> 6, lane = tid & 63, ln = lane & 15, quad = lane >> 4;

    // ---- rounds ----
    for (int r = 0; r < NROUNDS; ++r) {
        if (tid < UB) {
            int i = bx * UB + tid;
            volatile const int* dr = (volatile const int*)done_round;
            bool ready = false;
            int a = depS[tid], b_ = depD[tid];
            if (dr[i] == NOTDONE) {
                ready = (a < 0 || dr[a] < r) && (b_ < 0 || dr[b_] < r);
            }
            int s = 0, d = 0; float dcs = 0.f, dcd = 0.f, e0 = 0.f, e1 = 0.f, e2 = 0.f;
            if (ready) {
                s = src[i]; d = dst[i];
                float t = (float)tsi[i];
                float lus = (a  >= 0) ? (float)tsi[a]  : lu0[s];
                float lud = (b_ >= 0) ? (float)tsi[b_] : lu0[d];
                dcs = expf(-ALPHA * fmaxf(t - lus, 0.f));
                dcd = expf(-ALPHA * fmaxf(t - lud, 0.f));
                e0 = ef[3 * i]; e1 = ef[3 * i + 1]; e2 = ef[3 * i + 2];
            }
            sA[tid] = s; dA[tid] = d; actA[tid] = ready ? 1 : 0;
            decS[tid] = dcs; decD[tid] = dcd;
            efs[tid][0] = e0; efs[tid][1] = e1; efs[tid][2] = e2;
        }
        __syncthreads();
        int anyact = 0;
        #pragma unroll
        for (int u = 0; u < UB; ++u) anyact += actA[u];

        if (anyact) {
            // ---- stage decayed states as hi/lo bf16 (1024 items, 1/thread) ----
            {
                int u = tid >> 6, c4 = tid & 63;
                float4 vs = *((const float4*)(mem + (size_t)sA[u] * M) + c4);
                float4 vd = *((const float4*)(mem + (size_t)dA[u] * M) + c4);
                float ds_ = decS[u], dd_ = decD[u];
                short h0, h1_, h2, h3, l0, l1, l2, l3;
                split2(vs.x * ds_, h0, l0); split2(vs.y * ds_, h1_, l1);
                split2(vs.z * ds_, h2, l2); split2(vs.w * ds_, h3, l3);
                short4v hv = {h0, h1_, h2, h3}, lv = {l0, l1, l2, l3};
                *(short4v*)&sh.g.psH[u * ROWP + c4 * 4] = hv;
                *(short4v*)&sh.g.psL[u * ROWP + c4 * 4] = lv;
                split2(vd.x * dd_, h0, l0); split2(vd.y * dd_, h1_, l1);
                split2(vd.z * dd_, h2, l2); split2(vd.w * dd_, h3, l3);
                short4v hv2 = {h0, h1_, h2, h3}, lv2 = {l0, l1, l2, l3};
                *(short4v*)&sh.g.pdH[u * ROWP + c4 * 4] = hv2;
                *(short4v*)&sh.g.pdL[u * ROWP + c4 * 4] = lv2;
            }
            __syncthreads();

            int n = wav * 16 + ln;

            // ---- GEMM1: h1 = relu([ps pd]@W1[:, :512]^T + ef@W1[:,512:]^T + b1) ----
            {
                f32x4 acc = {0, 0, 0, 0};
                for (int kb = 0; kb < 16; ++kb) {
                    const short* aHp = (kb < 8) ? sh.g.psH : sh.g.pdH;
                    const short* aLp = (kb < 8) ? sh.g.psL : sh.g.pdL;
                    int kk = (kb & 7) * 32 + quad * 8;
                    short8 ah = *(const short8*)&aHp[ln * ROWP + kk];
                    short8 al = *(const short8*)&aLp[ln * ROWP + kk];
                    short8 bfr = *(const short8*)(W1h + (size_t)n * 512 + kb * 32 + quad * 8);
                    acc = __builtin_amdgcn_mfma_f32_16x16x32_bf16(ah, bfr, acc, 0, 0, 0);
                    acc = __builtin_amdgcn_mfma_f32_16x16x32_bf16(al, bfr, acc, 0, 0, 0);
                }
                float bv = b1[n];
                float w0 = W1g[n * 515 + 512], w1 = W1g[n * 515 + 513], w2 = W1g[n * 515 + 514];
                #pragma unroll
                for (int reg = 0; reg < 4; ++reg) {
                    int m = quad * 4 + reg;
                    float v = acc[reg] + bv + w0 * efs[m][0] + w1 * efs[m][1] + w2 * efs[m][2];
                    v = fmaxf(v, 0.f);
                    short hi, lo; split2(v, hi, lo);
                    sh.g.xH[m * ROWP + n] = hi; sh.g.xL[m * ROWP + n] = lo;
                }
            }
            __syncthreads();

            // ---- GEMM2: msg = h1 @ W2^T + b2 ----
            {
                f32x4 acc = {0, 0, 0, 0};
                for (int kb = 0; kb < 8; ++kb) {
                    int kk = kb * 32 + quad * 8;
                    short8 ah = *(const short8*)&sh.g.xH[ln * ROWP + kk];
                    short8 al = *(const short8*)&sh.g.xL[ln * ROWP + kk];
                    short8 bfr = *(const short8*)(W2h + (size_t)n * 256 + kk);
                    acc = __builtin_amdgcn_mfma_f32_16x16x32_bf16(ah, bfr, acc, 0, 0, 0);
                    acc = __builtin_amdgcn_mfma_f32_16x16x32_bf16(al, bfr, acc, 0, 0, 0);
                }
                __syncthreads();   // all h1 reads complete before overwrite
                float bv = b2[n];
                #pragma unroll
                for (int reg = 0; reg < 4; ++reg) {
                    int m = quad * 4 + reg;
                    float v = acc[reg] + bv;
                    short hi, lo; split2(v, hi, lo);
                    sh.g.xH[m * ROWP + n] = hi; sh.g.xL[m * ROWP + n] = lo;
                }
            }
            __syncthreads();

            // ---- GEMM3 + GRU epilogue: 9 gate tiles, all in-register ----
            {
                f32x4 aIR = {0,0,0,0}, aIZ = {0,0,0,0}, aIN = {0,0,0,0};
                f32x4 aSR = {0,0,0,0}, aSZ = {0,0,0,0}, aSN = {0,0,0,0};
                f32x4 aDR = {0,0,0,0}, aDZ = {0,0,0,0}, aDN = {0,0,0,0};
                for (int kb = 0; kb < 8; ++kb) {
                    int kk = kb * 32 + quad * 8;
                    short8 xmh = *(const short8*)&sh.g.xH[ln * ROWP + kk];
                    short8 xml = *(const short8*)&sh.g.xL[ln * ROWP + kk];
                    short8 xsh = *(const short8*)&sh.g.psH[ln * ROWP + kk];
                    short8 xsl = *(const short8*)&sh.g.psL[ln * ROWP + kk];
                    short8 xdh = *(const short8*)&sh.g.pdH[ln * ROWP + kk];
                    short8 xdl = *(const short8*)&sh.g.pdL[ln * ROWP + kk];
                    short8 bir = *(const short8*)(wihH + (size_t)n * 256 + kk);
                    short8 biz = *(const short8*)(wihH + (size_t)(n + 256) * 256 + kk);
                    short8 bin = *(const short8*)(wihH + (size_t)(n + 512) * 256 + kk);
                    short8 bhr = *(const short8*)(whhH + (size_t)n * 256 + kk);
                    short8 bhz = *(const short8*)(whhH + (size_t)(n + 256) * 256 + kk);
                    short8 bhn = *(const short8*)(whhH + (size_t)(n + 512) * 256 + kk);
                    aIR = __builtin_amdgcn_mfma_f32_16x16x32_bf16(xmh, bir, aIR, 0, 0, 0);
                    aIR = __builtin_amdgcn_mfma_f32_16x16x32_bf16(xml, bir, aIR, 0, 0, 0);
                    aIZ = __builtin_amdgcn_mfma_f32_16x16x32_bf16(xmh, biz, aIZ, 0, 0, 0);
                    aIZ = __builtin_amdgcn_mfma_f32_16x16x32_bf16(xml, biz, aIZ, 0, 0, 0);
                    aIN = __builtin_amdgcn_mfma_f32_16x16x32_bf16(xmh, bin, aIN, 0, 0, 0);
                    aIN = __builtin_amdgcn_mfma_f32_16x16x32_bf16(xml, bin, aIN, 0, 0, 0);
                    aSR = __builtin_amdgcn_mfma_f32_16x16x32_bf16(xsh, bhr, aSR, 0, 0, 0);
                    aSR = __builtin_amdgcn_mfma_f32_16x16x32_bf16(xsl, bhr, aSR, 0, 0, 0);
                    aSZ = __builtin_amdgcn_mfma_f32_16x16x32_bf16(xsh, bhz, aSZ, 0, 0, 0);
                    aSZ = __builtin_amdgcn_mfma_f32_16x16x32_bf16(xsl, bhz, aSZ, 0, 0, 0);
                    aSN = __builtin_amdgcn_mfma_f32_16x16x32_bf16(xsh, bhn, aSN, 0, 0, 0);
                    aSN = __builtin_amdgcn_mfma_f32_16x16x32_bf16(xsl, bhn, aSN, 0, 0, 0);
                    aDR = __builtin_amdgcn_mfma_f32_16x16x32_bf16(xdh, bhr, aDR, 0, 0, 0);
                    aDR = __builtin_amdgcn_mfma_f32_16x16x32_bf16(xdl, bhr, aDR, 0, 0, 0);
                    aDZ = __builtin_amdgcn_mfma_f32_16x16x32_bf16(xdh, bhz, aDZ, 0, 0, 0);
                    aDZ = __builtin_amdgcn_mfma_f32_16x16x32_bf16(xdl, bhz, aDZ, 0, 0, 0);
                    aDN = __builtin_amdgcn_mfma_f32_16x16x32_bf16(xdh, bhn, aDN, 0, 0, 0);
                    aDN = __builtin_amdgcn_mfma_f32_16x16x32_bf16(xdl, bhn, aDN, 0, 0, 0);
                }
                float bir_ = bih[n], biz_ = bih[M + n], bin_ = bih[2 * M + n];
                float bhr_ = bhh[n], bhz_ = bhh[M + n], bhn_ = bhh[2 * M + n];
                #pragma unroll
                for (int reg = 0; reg < 4; ++reg) {
                    int m = quad * 4 + reg;
                    if (actA[m]) {
                        float gir = aIR[reg] + bir_;
                        float giz = aIZ[reg] + biz_;
                        float gin = aIN[reg] + bin_;
                        float hs = bf2f(sh.g.psH[m * ROWP + n]) + bf2f(sh.g.psL[m * ROWP + n]);
                        float hd = bf2f(sh.g.pdH[m * ROWP + n]) + bf2f(sh.g.pdL[m * ROWP + n]);
                        float rs_ = 1.f / (1.f + expf(-(gir + aSR[reg] + bhr_)));
                        float zs_ = 1.f / (1.f + expf(-(giz + aSZ[reg] + bhz_)));
                        float ns_ = tanhf(gin + rs_ * (aSN[reg] + bhn_));
                        float us  = (1.f - zs_) * ns_ + zs_ * hs;
                        float rd_ = 1.f / (1.f + expf(-(gir + aDR[reg] + bhr_)));
                        float zd_ = 1.f / (1.f + expf(-(giz + aDZ[reg] + bhz_)));
                        float nd_ = tanhf(gin + rd_ * (aDN[reg] + bhn_));
                        float ud  = (1.f - zd_) * nd_ + zd_ * hd;
                        int s = sA[m], d = dA[m];
                        if (s != d) mem[(size_t)s * M + n] = us;
                        mem[(size_t)d * M + n] = ud;
                    }
                }
            }
            if (tid < UB && actA[tid]) done_round[bx * UB + tid] = r;
        }
        __threadfence();
        grid.sync();
    }
}

// ---------------------------------------------------------------------------
extern "C" void kernel_launch(void* const* d_in, const int* in_sizes, int n_in,
                              void* d_out, int out_size, void* d_ws, size_t ws_size,
                              hipStream_t stream) {
    const int*   src   = (const int*)d_in[0];
    const int*   dst   = (const int*)d_in[1];
    const float* ef    = (const float*)d_in[2];
    const int*   tsi   = (const int*)d_in[3];
    const float* memin = (const float*)d_in[4];
    const float* lu0   = (const float*)d_in[5];
    const float* W1    = (const float*)d_in[6];
    const float* b1    = (const float*)d_in[7];
    const float* W2    = (const float*)d_in[8];
    const float* b2    = (const float*)d_in[9];
    const float* wih   = (const float*)d_in[10];
    const float* whh   = (const float*)d_in[11];
    const float* bih   = (const float*)d_in[12];
    const float* bhh   = (const float*)d_in[13];
    float* mem = (float*)d_out;

    // ws carve (~1.2 MB)
    short* W1h  = (short*)d_ws;              // 256*512
    short* W2h  = W1h + 256 * 512;           // 256*256
    short* wihH = W2h + 256 * 256;           // 768*256
    short* whhH = wihH + 768 * 256;          // 768*256
    int* done_round = (int*)(whhH + 768 * 256);

    hipMemcpyAsync(mem, memin, (size_t)NNODES * M * sizeof(float),
                   hipMemcpyDeviceToDevice, stream);

    void* args[] = { (void*)&src, (void*)&dst, (void*)&ef, (void*)&tsi, (void*)&lu0,
                     (void*)&W1, (void*)&W2, (void*)&wih, (void*)&whh,
                     (void*)&b1, (void*)&b2, (void*)&bih, (void*)&bhh,
                     (void*)&W1h, (void*)&W2h, (void*)&wihH, (void*)&whhH,
                     (void*)&done_round, (void*)&mem };
    hipLaunchCooperativeKernel((void*)tgn_main, dim3(NBLK), dim3(NTHR), args, 0, stream);
}

// Round 4
// 388.423 us; speedup vs baseline: 4.0314x; 4.0314x over previous
//
#include <hip/hip_runtime.h>
#include <math.h>

#define NNODES 100000
#define B 4096
#define M 256
#define UB 16
#define NROUNDS 10
#define NOTDONE 0x7fffffff
#define ALPHA 0.1f

typedef __attribute__((ext_vector_type(8))) short short8;
typedef __attribute__((ext_vector_type(4))) short short4v;
typedef __attribute__((ext_vector_type(4))) float f32x4;

__device__ __forceinline__ short bf16rne(float x) {
    union { float f; unsigned u; } v; v.f = x;
    unsigned r = v.u + 0x7fffu + ((v.u >> 16) & 1u);
    return (short)(r >> 16);
}
__device__ __forceinline__ float bf2f(short h) {
    union { unsigned u; float f; } v; v.u = ((unsigned)(unsigned short)h) << 16;
    return v.f;
}
__device__ __forceinline__ void split2(float x, short &hi, short &lo) {
    hi = bf16rne(x);
    lo = bf16rne(x - bf2f(hi));
}

// XOR swizzle on 16B chunks: kills the 8-way bank conflict of strided rows.
// row*256 + ((col/8) ^ (row%8))*8 + col%8   (cols per row = 256 shorts)
__device__ __forceinline__ int SW(int row, int col) {
    return row * 256 + ((((col) >> 3) ^ (row & 7)) << 3) + (col & 7);
}

// ---------------------------------------------------------------------------
// Prep: output copy, bf16 weight casts, flag init, wave-ballot dep scan.
// dep_s[i] = max j<i with s_j==s_i || d_j==s_i (else -1); dep_d likewise.
// ---------------------------------------------------------------------------
__global__ __launch_bounds__(1024) void tgn_prep(
    const int* __restrict__ src, const int* __restrict__ dst,
    const float* __restrict__ memin,
    const float* __restrict__ W1g, const float* __restrict__ W2g,
    const float* __restrict__ wihG, const float* __restrict__ whhG,
    short* __restrict__ W1h, short* __restrict__ W2h,
    short* __restrict__ wihH, short* __restrict__ whhH,
    int* __restrict__ dep_s, int* __restrict__ dep_d,
    int* __restrict__ done_round, int* __restrict__ n_done,
    float* __restrict__ mem)
{
    __shared__ int sL[B];
    __shared__ int dL[B];
    int tid = threadIdx.x, bx = blockIdx.x;
    int gtid = bx * 1024 + tid;
    const int G = 256 * 1024;

    for (int j = tid; j < B; j += 1024) { sL[j] = src[j]; dL[j] = dst[j]; }
    if (gtid < B) done_round[gtid] = NOTDONE;
    if (gtid == 0) *n_done = 0;
    for (int t = gtid; t < 256 * 512; t += G) {
        int n = t >> 9, k = t & 511;
        W1h[t] = bf16rne(W1g[n * 515 + k]);
    }
    for (int t = gtid; t < 256 * 256; t += G) W2h[t] = bf16rne(W2g[t]);
    for (int t = gtid; t < 768 * 256; t += G) {
        wihH[t] = bf16rne(wihG[t]); whhH[t] = bf16rne(whhG[t]);
    }
    __syncthreads();

    {   // one wave per step: lockstep backward scan, ballot for latest match
        int wv = tid >> 6, lane = tid & 63;
        int i = bx * UB + wv;
        int vs = sL[i], vd = dL[i];
        int bs = -1, bd = -1;
        for (int base = i - 1; base >= 0; base -= 64) {
            int j = base - lane;
            bool okj = (j >= 0);
            int sj = okj ? sL[j] : -1;
            int dj = okj ? dL[j] : -1;
            if (bs < 0) {
                unsigned long long mk = __ballot(okj && (sj == vs || dj == vs));
                if (mk) bs = base - (int)__builtin_ctzll(mk);
            }
            if (bd < 0) {
                unsigned long long mk = __ballot(okj && (sj == vd || dj == vd));
                if (mk) bd = base - (int)__builtin_ctzll(mk);
            }
            if (bs >= 0 && bd >= 0) break;
        }
        if (lane == 0) { dep_s[i] = bs; dep_d[i] = bd; }
    }

    // bulk output copy (float4 grid-stride)
    const float4* mi = (const float4*)memin;
    float4* mo = (float4*)mem;
    for (int t = gtid; t < NNODES * M / 4; t += G) mo[t] = mi[t];
}

// ---------------------------------------------------------------------------
// One round: block b owns steps [16b, 16b+16); wave w owns cols [16w, 16w+16).
// MFMA 16x16x32 bf16, hi/lo-split activations. Launch-boundary = coherence.
// ---------------------------------------------------------------------------
__global__ __launch_bounds__(1024, 4) void tgn_round(
    int r,
    const int* __restrict__ src, const int* __restrict__ dst,
    const float* __restrict__ ef, const int* __restrict__ tsi,
    const float* __restrict__ lu0,
    const float* __restrict__ W1g,
    const float* __restrict__ b1, const float* __restrict__ b2,
    const float* __restrict__ bih, const float* __restrict__ bhh,
    const short* __restrict__ W1h, const short* __restrict__ W2h,
    const short* __restrict__ wihH, const short* __restrict__ whhH,
    const int* __restrict__ dep_s, const int* __restrict__ dep_d,
    int* __restrict__ done_round, int* __restrict__ n_done,
    float* __restrict__ mem)
{
    __shared__ __align__(16) short psH[UB * 256];
    __shared__ __align__(16) short psL[UB * 256];
    __shared__ __align__(16) short pdH[UB * 256];
    __shared__ __align__(16) short pdL[UB * 256];
    __shared__ __align__(16) short xH[UB * 256];   // h1 then msg
    __shared__ __align__(16) short xL[UB * 256];
    __shared__ float efs[UB][3];
    __shared__ float decS[UB], decD[UB];
    __shared__ int sA[UB], dA[UB], actA[UB];
    __shared__ int nd_sh;

    int tid = threadIdx.x, bx = blockIdx.x;
    if (tid == 0) nd_sh = *n_done;
    __syncthreads();
    if (nd_sh >= B) return;          // uniform: all steps drained

    if (tid < UB) {
        int i = bx * UB + tid;
        bool ready = false;
        int a = dep_s[i], b_ = dep_d[i];
        if (done_round[i] == NOTDONE) {
            ready = (a < 0 || done_round[a] < r) && (b_ < 0 || done_round[b_] < r);
        }
        int s = 0, d = 0; float dcs = 0.f, dcd = 0.f, e0 = 0.f, e1 = 0.f, e2 = 0.f;
        if (ready) {
            s = src[i]; d = dst[i];
            float t = (float)tsi[i];
            float lus = (a  >= 0) ? (float)tsi[a]  : lu0[s];
            float lud = (b_ >= 0) ? (float)tsi[b_] : lu0[d];
            dcs = expf(-ALPHA * fmaxf(t - lus, 0.f));
            dcd = expf(-ALPHA * fmaxf(t - lud, 0.f));
            e0 = ef[3 * i]; e1 = ef[3 * i + 1]; e2 = ef[3 * i + 2];
        }
        sA[tid] = s; dA[tid] = d; actA[tid] = ready ? 1 : 0;
        decS[tid] = dcs; decD[tid] = dcd;
        efs[tid][0] = e0; efs[tid][1] = e1; efs[tid][2] = e2;
    }
    __syncthreads();
    int anyact = 0;
    #pragma unroll
    for (int u = 0; u < UB; ++u) anyact += actA[u];
    if (anyact == 0) return;         // uniform

    // ---- stage decayed states as hi/lo bf16 (1024 items, 1/thread) ----
    {
        int u = tid >> 6, c4 = tid & 63;
        float4 vs = *((const float4*)(mem + (size_t)sA[u] * M) + c4);
        float4 vd = *((const float4*)(mem + (size_t)dA[u] * M) + c4);
        float ds_ = decS[u], dd_ = decD[u];
        int p = SW(u, c4 * 4);
        short h0, h1_, h2, h3, l0, l1, l2, l3;
        split2(vs.x * ds_, h0, l0); split2(vs.y * ds_, h1_, l1);
        split2(vs.z * ds_, h2, l2); split2(vs.w * ds_, h3, l3);
        short4v hv = {h0, h1_, h2, h3}, lv = {l0, l1, l2, l3};
        *(short4v*)&psH[p] = hv;
        *(short4v*)&psL[p] = lv;
        split2(vd.x * dd_, h0, l0); split2(vd.y * dd_, h1_, l1);
        split2(vd.z * dd_, h2, l2); split2(vd.w * dd_, h3, l3);
        short4v hv2 = {h0, h1_, h2, h3}, lv2 = {l0, l1, l2, l3};
        *(short4v*)&pdH[p] = hv2;
        *(short4v*)&pdL[p] = lv2;
    }
    __syncthreads();

    int wav = tid >> 6, lane = tid & 63, ln = lane & 15, quad = lane >> 4;
    int n = wav * 16 + ln;

    // ---- GEMM1: h1 = relu([ps pd]@W1[:, :512]^T + ef@W1[:,512:]^T + b1) ----
    {
        f32x4 acc = {0, 0, 0, 0};
        for (int kb = 0; kb < 16; ++kb) {
            const short* aHp = (kb < 8) ? psH : pdH;
            const short* aLp = (kb < 8) ? psL : pdL;
            int p = SW(ln, (kb & 7) * 32 + quad * 8);
            short8 ah = *(const short8*)&aHp[p];
            short8 al = *(const short8*)&aLp[p];
            short8 bfr = *(const short8*)(W1h + (size_t)n * 512 + kb * 32 + quad * 8);
            acc = __builtin_amdgcn_mfma_f32_16x16x32_bf16(ah, bfr, acc, 0, 0, 0);
            acc = __builtin_amdgcn_mfma_f32_16x16x32_bf16(al, bfr, acc, 0, 0, 0);
        }
        float bv = b1[n];
        float w0 = W1g[n * 515 + 512], w1 = W1g[n * 515 + 513], w2 = W1g[n * 515 + 514];
        #pragma unroll
        for (int reg = 0; reg < 4; ++reg) {
            int m = quad * 4 + reg;
            float v = acc[reg] + bv + w0 * efs[m][0] + w1 * efs[m][1] + w2 * efs[m][2];
            v = fmaxf(v, 0.f);
            short hi, lo; split2(v, hi, lo);
            int p = SW(m, n);
            xH[p] = hi; xL[p] = lo;
        }
    }
    __syncthreads();

    // ---- GEMM2: msg = h1 @ W2^T + b2 ----
    {
        f32x4 acc = {0, 0, 0, 0};
        for (int kb = 0; kb < 8; ++kb) {
            int p = SW(ln, kb * 32 + quad * 8);
            short8 ah = *(const short8*)&xH[p];
            short8 al = *(const short8*)&xL[p];
            short8 bfr = *(const short8*)(W2h + (size_t)n * 256 + kb * 32 + quad * 8);
            acc = __builtin_amdgcn_mfma_f32_16x16x32_bf16(ah, bfr, acc, 0, 0, 0);
            acc = __builtin_amdgcn_mfma_f32_16x16x32_bf16(al, bfr, acc, 0, 0, 0);
        }
        __syncthreads();   // all h1 reads complete before overwrite
        float bv = b2[n];
        #pragma unroll
        for (int reg = 0; reg < 4; ++reg) {
            int m = quad * 4 + reg;
            float v = acc[reg] + bv;
            short hi, lo; split2(v, hi, lo);
            int p = SW(m, n);
            xH[p] = hi; xL[p] = lo;
        }
    }
    __syncthreads();

    // ---- GEMM3 + GRU epilogue: 9 gate tiles, all in-register ----
    {
        f32x4 aIR = {0,0,0,0}, aIZ = {0,0,0,0}, aIN = {0,0,0,0};
        f32x4 aSR = {0,0,0,0}, aSZ = {0,0,0,0}, aSN = {0,0,0,0};
        f32x4 aDR = {0,0,0,0}, aDZ = {0,0,0,0}, aDN = {0,0,0,0};
        for (int kb = 0; kb < 8; ++kb) {
            int kk = kb * 32 + quad * 8;
            int p = SW(ln, kk);
            short8 xmh = *(const short8*)&xH[p];
            short8 xml = *(const short8*)&xL[p];
            short8 xsh = *(const short8*)&psH[p];
            short8 xsl = *(const short8*)&psL[p];
            short8 xdh = *(const short8*)&pdH[p];
            short8 xdl = *(const short8*)&pdL[p];
            short8 bir = *(const short8*)(wihH + (size_t)n * 256 + kk);
            short8 biz = *(const short8*)(wihH + (size_t)(n + 256) * 256 + kk);
            short8 bin = *(const short8*)(wihH + (size_t)(n + 512) * 256 + kk);
            short8 bhr = *(const short8*)(whhH + (size_t)n * 256 + kk);
            short8 bhz = *(const short8*)(whhH + (size_t)(n + 256) * 256 + kk);
            short8 bhn = *(const short8*)(whhH + (size_t)(n + 512) * 256 + kk);
            aIR = __builtin_amdgcn_mfma_f32_16x16x32_bf16(xmh, bir, aIR, 0, 0, 0);
            aIR = __builtin_amdgcn_mfma_f32_16x16x32_bf16(xml, bir, aIR, 0, 0, 0);
            aIZ = __builtin_amdgcn_mfma_f32_16x16x32_bf16(xmh, biz, aIZ, 0, 0, 0);
            aIZ = __builtin_amdgcn_mfma_f32_16x16x32_bf16(xml, biz, aIZ, 0, 0, 0);
            aIN = __builtin_amdgcn_mfma_f32_16x16x32_bf16(xmh, bin, aIN, 0, 0, 0);
            aIN = __builtin_amdgcn_mfma_f32_16x16x32_bf16(xml, bin, aIN, 0, 0, 0);
            aSR = __builtin_amdgcn_mfma_f32_16x16x32_bf16(xsh, bhr, aSR, 0, 0, 0);
            aSR = __builtin_amdgcn_mfma_f32_16x16x32_bf16(xsl, bhr, aSR, 0, 0, 0);
            aSZ = __builtin_amdgcn_mfma_f32_16x16x32_bf16(xsh, bhz, aSZ, 0, 0, 0);
            aSZ = __builtin_amdgcn_mfma_f32_16x16x32_bf16(xsl, bhz, aSZ, 0, 0, 0);
            aSN = __builtin_amdgcn_mfma_f32_16x16x32_bf16(xsh, bhn, aSN, 0, 0, 0);
            aSN = __builtin_amdgcn_mfma_f32_16x16x32_bf16(xsl, bhn, aSN, 0, 0, 0);
            aDR = __builtin_amdgcn_mfma_f32_16x16x32_bf16(xdh, bhr, aDR, 0, 0, 0);
            aDR = __builtin_amdgcn_mfma_f32_16x16x32_bf16(xdl, bhr, aDR, 0, 0, 0);
            aDZ = __builtin_amdgcn_mfma_f32_16x16x32_bf16(xdh, bhz, aDZ, 0, 0, 0);
            aDZ = __builtin_amdgcn_mfma_f32_16x16x32_bf16(xdl, bhz, aDZ, 0, 0, 0);
            aDN = __builtin_amdgcn_mfma_f32_16x16x32_bf16(xdh, bhn, aDN, 0, 0, 0);
            aDN = __builtin_amdgcn_mfma_f32_16x16x32_bf16(xdl, bhn, aDN, 0, 0, 0);
        }
        float bir_ = bih[n], biz_ = bih[M + n], bin_ = bih[2 * M + n];
        float bhr_ = bhh[n], bhz_ = bhh[M + n], bhn_ = bhh[2 * M + n];
        #pragma unroll
        for (int reg = 0; reg < 4; ++reg) {
            int m = quad * 4 + reg;
            if (actA[m]) {
                int p = SW(m, n);
                float gir = aIR[reg] + bir_;
                float giz = aIZ[reg] + biz_;
                float gin = aIN[reg] + bin_;
                float hs = bf2f(psH[p]) + bf2f(psL[p]);
                float hd = bf2f(pdH[p]) + bf2f(pdL[p]);
                float rs_ = 1.f / (1.f + expf(-(gir + aSR[reg] + bhr_)));
                float zs_ = 1.f / (1.f + expf(-(giz + aSZ[reg] + bhz_)));
                float ns_ = tanhf(gin + rs_ * (aSN[reg] + bhn_));
                float us  = (1.f - zs_) * ns_ + zs_ * hs;
                float rd_ = 1.f / (1.f + expf(-(gir + aDR[reg] + bhr_)));
                float zd_ = 1.f / (1.f + expf(-(giz + aDZ[reg] + bhz_)));
                float nd_ = tanhf(gin + rd_ * (aDN[reg] + bhn_));
                float ud  = (1.f - zd_) * nd_ + zd_ * hd;
                int s = sA[m], d = dA[m];
                if (s != d) mem[(size_t)s * M + n] = us;
                mem[(size_t)d * M + n] = ud;
            }
        }
    }
    if (tid < UB && actA[tid]) {
        done_round[bx * UB + tid] = r;
        atomicAdd(n_done, 1);
    }
}

// ---------------------------------------------------------------------------
extern "C" void kernel_launch(void* const* d_in, const int* in_sizes, int n_in,
                              void* d_out, int out_size, void* d_ws, size_t ws_size,
                              hipStream_t stream) {
    const int*   src   = (const int*)d_in[0];
    const int*   dst   = (const int*)d_in[1];
    const float* ef    = (const float*)d_in[2];
    const int*   tsi   = (const int*)d_in[3];
    const float* memin = (const float*)d_in[4];
    const float* lu0   = (const float*)d_in[5];
    const float* W1    = (const float*)d_in[6];
    const float* b1    = (const float*)d_in[7];
    const float* W2    = (const float*)d_in[8];
    const float* b2    = (const float*)d_in[9];
    const float* wih   = (const float*)d_in[10];
    const float* whh   = (const float*)d_in[11];
    const float* bih   = (const float*)d_in[12];
    const float* bhh   = (const float*)d_in[13];
    float* mem = (float*)d_out;

    // ws carve (~1.2 MB)
    short* W1h  = (short*)d_ws;              // 256*512
    short* W2h  = W1h + 256 * 512;           // 256*256
    short* wihH = W2h + 256 * 256;           // 768*256
    short* whhH = wihH + 768 * 256;          // 768*256
    int* dep_s      = (int*)(whhH + 768 * 256);
    int* dep_d      = dep_s + B;
    int* done_round = dep_d + B;
    int* n_done     = done_round + B;

    tgn_prep<<<256, 1024, 0, stream>>>(src, dst, memin, W1, W2, wih, whh,
                                       W1h, W2h, wihH, whhH,
                                       dep_s, dep_d, done_round, n_done, mem);
    for (int r = 0; r < NROUNDS; ++r) {
        tgn_round<<<B / UB, 1024, 0, stream>>>(
            r, src, dst, ef, tsi, lu0, W1, b1, b2, bih, bhh,
            W1h, W2h, wihH, whhH, dep_s, dep_d, done_round, n_done, mem);
    }
}